// Round 2
// baseline (501.328 us; speedup 1.0000x reference)
//
#include <hip/hip_runtime.h>
#include <hip/hip_bf16.h>
#include <stdint.h>

typedef short s16x8 __attribute__((ext_vector_type(8)));
typedef float f32x4 __attribute__((ext_vector_type(4)));
typedef unsigned int u32;
typedef unsigned short u16;

#define CCH 192
#define TTILE 128
#define APITCH 200   // bf16 elems per LDS row; 400B pitch -> 2-way bank alias only (free)
#define NCODES 128

__device__ __forceinline__ u16 f2b(float f) {
  u32 u = __builtin_bit_cast(u32, f);
  u = (u + 0x7fffu + ((u >> 16) & 1u)) >> 16;   // RNE
  return (u16)u;
}
__device__ __forceinline__ float b2f(u16 h) {
  return __builtin_bit_cast(float, ((u32)h) << 16);
}

// ---- x (B,C,T) f32 -> xt (B,T,C) bf16 ----
__global__ __launch_bounds__(256) void k_tin(const float* __restrict__ x, u16* __restrict__ xt,
                                             int B, int T) {
  __shared__ float tile[32][36];
  int nt = T >> 5;
  int bid = blockIdx.x;
  int b = bid / (6 * nt);
  int rem = bid % (6 * nt);
  int cb = rem / nt, tb = rem % nt;
  int tid = threadIdx.x;
  {
    int c = tid >> 3, seg = tid & 7;
    const float* src = x + ((size_t)b * CCH + cb * 32 + c) * T + tb * 32 + seg * 4;
    float4 v = *(const float4*)src;
    tile[c][seg * 4 + 0] = v.x; tile[c][seg * 4 + 1] = v.y;
    tile[c][seg * 4 + 2] = v.z; tile[c][seg * 4 + 3] = v.w;
  }
  __syncthreads();
  {
    int t = tid >> 3, cs = tid & 7;
    u16* dst = xt + ((size_t)b * T + tb * 32 + t) * CCH + cb * 32 + cs * 4;
    ushort4 o;
    o.x = f2b(tile[cs * 4 + 0][t]); o.y = f2b(tile[cs * 4 + 1][t]);
    o.z = f2b(tile[cs * 4 + 2][t]); o.w = f2b(tile[cs * 4 + 3][t]);
    *(ushort4*)dst = o;
  }
}

// ---- weights (O,I,3) f32 -> (3,O,I) bf16 ----
__global__ __launch_bounds__(256) void k_wconv(const float* __restrict__ w, u16* __restrict__ dst) {
  int i = blockIdx.x * 256 + threadIdx.x;
  if (i >= 3 * CCH * CCH) return;
  int k = i / (CCH * CCH);
  int rem = i - k * (CCH * CCH);
  int o = rem / CCH, ii = rem - o * CCH;
  dst[i] = f2b(w[(o * CCH + ii) * 3 + k]);
}

// ---- emb (K,C) f32 -> bf16 + ||e||^2 f32 ----
__global__ __launch_bounds__(64) void k_emb(const float* __restrict__ emb, u16* __restrict__ embb,
                                            float* __restrict__ e2) {
  int code = blockIdx.x, lane = threadIdx.x;
  float s = 0.f;
  for (int j = lane * 3; j < lane * 3 + 3; ++j) {
    float v = emb[code * CCH + j];
    embb[code * CCH + j] = f2b(v);
    s += v * v;
  }
  #pragma unroll
  for (int m = 1; m < 64; m <<= 1) s += __shfl_xor(s, m, 64);
  if (lane == 0) e2[code] = s;
}

__global__ void k_zero(int* hist, double* dsum) {
  int t = threadIdx.x;
  if (t < NCODES) hist[t] = 0;
  if (t == 0) *dsum = 0.0;
}

// ---- conv1d k=3 same-pad as 3 shifted GEMMs; in/out (B,T,C) bf16 ----
// Tile: 128 tokens x 192 outs, 4 waves N-split (48 outs each), acc[8][3].
// OUTM=0: bf16 (B,T,C) out via LDS-bounce, coalesced 16B stores.
// OUTM=1: f32 (B,C,T) out via 2-pass f32 LDS transpose (dec3 -> d_out+1).
template<bool RELU, int OUTM>
__global__ __launch_bounds__(256, 3) void k_conv(const u16* __restrict__ in, const u16* __restrict__ wk,
                                                 const float* __restrict__ bias, void* __restrict__ outp,
                                                 int B, int T) {
  // A tile: 130 rows x APITCH*2 = 52000 B; epilogue reuses the same buffer.
  __shared__ __align__(16) char smem[(TTILE + 2) * APITCH * 2];
  u16* alds = (u16*)smem;
  int tid = threadIdx.x;
  int bid = blockIdx.x;
  int ntb = T / TTILE;
  int b = bid / ntb, tblk = bid % ntb;
  int t0 = tblk * TTILE;
  const u16* src = in + (size_t)b * T * CCH;
  // stage rows t0-1 .. t0+128 (130 rows x 192ch) with zero padding at batch edges
  for (int s = tid; s < (TTILE + 2) * 24; s += 256) {
    int row = s / 24, seg = s - row * 24;
    int tg = t0 + row - 1;
    uint4 v = {0u, 0u, 0u, 0u};
    if (tg >= 0 && tg < T) v = *(const uint4*)(src + (size_t)tg * CCH + seg * 8);
    *(uint4*)(alds + row * APITCH + seg * 8) = v;
  }
  __syncthreads();
  int wv = tid >> 6, lane = tid & 63, lr = lane & 15, lg = lane >> 4;
  int oB = wv * 48;
  const u16* abase = alds + lr * APITCH + lg * 8;          // + (mf*16+k)*APITCH + ci
  const u16* wbase = wk + (size_t)(oB + lr) * CCH + lg * 8; // + (k*CCH + nf*16)*CCH + ci
  f32x4 acc[8][3] = {};
  #pragma unroll
  for (int cb = 0; cb < 6; ++cb) {
    const int ci = cb * 32;
    #pragma unroll
    for (int k = 0; k < 3; ++k) {
      s16x8 a[8];
      #pragma unroll
      for (int mf = 0; mf < 8; ++mf)
        a[mf] = *(const s16x8*)(abase + (mf * 16 + k) * APITCH + ci);
      #pragma unroll
      for (int nf = 0; nf < 3; ++nf) {
        s16x8 bf = *(const s16x8*)(wbase + (size_t)(k * CCH + nf * 16) * CCH + ci);
        #pragma unroll
        for (int mf = 0; mf < 8; ++mf)
          acc[mf][nf] = __builtin_amdgcn_mfma_f32_16x16x32_bf16(a[mf], bf, acc[mf][nf], 0, 0, 0);
      }
    }
  }
  float bv[3];
  #pragma unroll
  for (int nf = 0; nf < 3; ++nf) bv[nf] = bias[oB + nf * 16 + lr];

  if (OUTM == 0) {
    __syncthreads();               // done reading A tile
    u16* obuf = alds;              // [128][APITCH] bf16
    #pragma unroll
    for (int mf = 0; mf < 8; ++mf) {
      #pragma unroll
      for (int nf = 0; nf < 3; ++nf) {
        int o = oB + nf * 16 + lr;
        #pragma unroll
        for (int r = 0; r < 4; ++r) {
          int t = mf * 16 + lg * 4 + r;
          float v = acc[mf][nf][r] + bv[nf];
          if (RELU) v = fmaxf(v, 0.f);
          obuf[t * APITCH + o] = f2b(v);
        }
      }
    }
    __syncthreads();
    u16* dst = (u16*)outp + (size_t)b * T * CCH + (size_t)t0 * CCH;
    for (int s = tid; s < TTILE * 24; s += 256) {
      int row = s >> 5; int seg = s & 31;   // NOTE: 24 segs -> use div below instead
      row = s / 24; seg = s - row * 24;
      uint4 v = *(const uint4*)(obuf + row * APITCH + seg * 8);
      *(uint4*)(dst + (size_t)row * CCH + seg * 8) = v;
    }
  } else {
    // f32 (B,C,T) out, two 64-token passes through a [192][66] f32 LDS tile
    float* ft = (float*)smem;
    float* dstb = (float*)outp + (size_t)b * CCH * T + t0;
    #pragma unroll
    for (int p = 0; p < 2; ++p) {
      __syncthreads();
      #pragma unroll
      for (int mf = 0; mf < 4; ++mf) {
        #pragma unroll
        for (int nf = 0; nf < 3; ++nf) {
          int o = oB + nf * 16 + lr;
          #pragma unroll
          for (int r = 0; r < 4; ++r) {
            int tl = mf * 16 + lg * 4 + r;
            ft[o * 66 + tl] = acc[p * 4 + mf][nf][r] + bv[nf];
          }
        }
      }
      __syncthreads();
      // coalesced scalar f32 stores (d_out+1 is only 4B-aligned)
      for (int s = tid; s < CCH * 64; s += 256) {
        int o = s >> 6, tl = s & 63;
        dstb[(size_t)o * T + p * 64 + tl] = ft[o * 66 + tl];
      }
    }
  }
}

// ---- VQ: distances (MFMA Z.E^T), argmin, loss sum + histogram ----
__global__ __launch_bounds__(256) void k_vq(const u16* __restrict__ zbf, const u16* __restrict__ embb,
                                            const float* __restrict__ e2, int* __restrict__ hist,
                                            double* __restrict__ dsum, int N) {
  __shared__ int hs[NCODES];
  __shared__ float wsum[4];
  int tid = threadIdx.x;
  if (tid < NCODES) hs[tid] = 0;
  __syncthreads();
  int wv = tid >> 6, lane = tid & 63, lr = lane & 15, lg = lane >> 4;
  int n0 = blockIdx.x * 64 + wv * 16;
  f32x4 acc[8] = {};
  for (int ci = 0; ci < CCH; ci += 32) {
    s16x8 a = *(const s16x8*)(zbf + (size_t)(n0 + lr) * CCH + ci + lg * 8);
    #pragma unroll
    for (int nf = 0; nf < 8; ++nf) {
      s16x8 bf = *(const s16x8*)(embb + (nf * 16 + lr) * CCH + ci + lg * 8);
      acc[nf] = __builtin_amdgcn_mfma_f32_16x16x32_bf16(a, bf, acc[nf], 0, 0, 0);
    }
  }
  float z2 = 0.f;
  const u16* zr = zbf + (size_t)(n0 + lr) * CCH + lg * 48;
  #pragma unroll
  for (int j = 0; j < 48; j += 8) {
    s16x8 v = *(const s16x8*)(zr + j);
    #pragma unroll
    for (int e = 0; e < 8; ++e) { float f = b2f((u16)v[e]); z2 += f * f; }
  }
  z2 += __shfl_xor(z2, 16, 64);
  z2 += __shfl_xor(z2, 32, 64);
  float smin[4]; int imin[4];
  #pragma unroll
  for (int r = 0; r < 4; ++r) { smin[r] = 3.4e38f; imin[r] = 0; }
  #pragma unroll
  for (int nf = 0; nf < 8; ++nf) {
    int code = nf * 16 + lr;
    float ev = e2[code];
    #pragma unroll
    for (int r = 0; r < 4; ++r) {
      float sc = ev - 2.f * acc[nf][r];
      if (sc < smin[r]) { smin[r] = sc; imin[r] = code; }
    }
  }
  #pragma unroll
  for (int m = 1; m < 16; m <<= 1) {
    #pragma unroll
    for (int r = 0; r < 4; ++r) {
      float so = __shfl_xor(smin[r], m, 64);
      int io = __shfl_xor(imin[r], m, 64);
      if (so < smin[r] || (so == smin[r] && io < imin[r])) { smin[r] = so; imin[r] = io; }
    }
  }
  float z2t[4];
  #pragma unroll
  for (int r = 0; r < 4; ++r) z2t[r] = __shfl(z2, lg * 4 + r, 64);
  float dpart = 0.f;
  if (lr == 0) {
    #pragma unroll
    for (int r = 0; r < 4; ++r) {
      dpart += z2t[r] + smin[r];
      atomicAdd(&hs[imin[r]], 1);
    }
  }
  #pragma unroll
  for (int m = 1; m < 64; m <<= 1) dpart += __shfl_xor(dpart, m, 64);
  if (lane == 0) wsum[wv] = dpart;
  __syncthreads();
  if (tid == 0) {
    double tot = (double)wsum[0] + (double)wsum[1] + (double)wsum[2] + (double)wsum[3];
    atomicAdd(dsum, tot);
  }
  if (tid < NCODES && hs[tid] > 0) atomicAdd(&hist[tid], hs[tid]);
}

__global__ __launch_bounds__(128) void k_fin(const int* __restrict__ hist,
                                             const double* __restrict__ dsum,
                                             float* __restrict__ out, int N, int ppos) {
  __shared__ float H[NCODES];
  int t = threadIdx.x;
  float p = (float)hist[t] / (float)N;
  H[t] = p * logf(p + 1e-10f);
  __syncthreads();
  if (t == 0) {
    float s = 0.f;
    for (int i = 0; i < NCODES; ++i) s += H[i];
    out[ppos] = expf(-s);
    out[0] = (float)(1.25 * (*dsum) / ((double)N * (double)CCH));
  }
}

extern "C" void kernel_launch(void* const* d_in, const int* in_sizes, int n_in,
                              void* d_out, int out_size, void* d_ws, size_t ws_size,
                              hipStream_t stream) {
  const int B = 16, T = 8192, N = B * T;
  const float* x   = (const float*)d_in[0];
  const float* ew1 = (const float*)d_in[1];
  const float* eb1 = (const float*)d_in[2];
  const float* ew2 = (const float*)d_in[3];
  const float* eb2 = (const float*)d_in[4];
  const float* emb = (const float*)d_in[5];
  const float* dw1 = (const float*)d_in[6];
  const float* db1 = (const float*)d_in[7];
  const float* dw2 = (const float*)d_in[8];
  const float* db2 = (const float*)d_in[9];
  const float* dw3 = (const float*)d_in[10];
  const float* db3 = (const float*)d_in[11];

  char* ws = (char*)d_ws;
  const size_t actSz = (size_t)B * T * CCH * 2;
  const int WE = 3 * CCH * CCH;
  u16* bufA = (u16*)ws;
  u16* bufB = (u16*)(ws + actSz);
  u16* wts  = (u16*)(ws + 2 * actSz);
  u16* embb = (u16*)(ws + 2 * actSz + (size_t)5 * WE * 2);
  float* e2 = (float*)((char*)embb + (size_t)NCODES * CCH * 2);
  int* hist = (int*)((char*)e2 + 512);
  double* dsum = (double*)((char*)hist + 512);

  const int wblocks = (3 * CCH * CCH + 255) / 256;
  k_wconv<<<wblocks, 256, 0, stream>>>(ew1, wts);
  k_wconv<<<wblocks, 256, 0, stream>>>(ew2, wts + WE);
  k_wconv<<<wblocks, 256, 0, stream>>>(dw1, wts + 2 * WE);
  k_wconv<<<wblocks, 256, 0, stream>>>(dw2, wts + 3 * WE);
  k_wconv<<<wblocks, 256, 0, stream>>>(dw3, wts + 4 * WE);
  k_emb<<<NCODES, 64, 0, stream>>>(emb, embb, e2);
  k_zero<<<1, 256, 0, stream>>>(hist, dsum);
  k_tin<<<B * 6 * (T / 32), 256, 0, stream>>>(x, bufA, B, T);

  const int cgrid = B * (T / TTILE);                  // 1024
  k_conv<true, 0><<<cgrid, 256, 0, stream>>>(bufA, wts, eb1, bufB, B, T);
  k_conv<false, 0><<<cgrid, 256, 0, stream>>>(bufB, wts + WE, eb2, bufA, B, T);
  k_vq<<<N / 64, 256, 0, stream>>>(bufA, embb, e2, hist, dsum, N);
  k_conv<true, 0><<<cgrid, 256, 0, stream>>>(bufA, wts + 2 * WE, db1, bufB, B, T);
  k_conv<true, 0><<<cgrid, 256, 0, stream>>>(bufB, wts + 3 * WE, db2, bufA, B, T);
  k_conv<false, 1><<<cgrid, 256, 0, stream>>>(bufA, wts + 4 * WE, db3, (float*)d_out + 1, B, T);
  k_fin<<<1, 128, 0, stream>>>(hist, dsum, (float*)d_out, N, out_size - 1);
}

// Round 3
// 422.560 us; speedup vs baseline: 1.1864x; 1.1864x over previous
//
#include <hip/hip_runtime.h>
#include <hip/hip_bf16.h>
#include <stdint.h>

typedef short s16x8 __attribute__((ext_vector_type(8)));
typedef float f32x4 __attribute__((ext_vector_type(4)));
typedef unsigned int u32;
typedef unsigned short u16;

#define CCH 192
#define APITCH 200   // bf16 elems per LDS row; 400B pitch -> 2-way bank alias only (free)
#define NCODES 128
#define HALO 9
#define ROWS 82      // staged rows: tokens t0-9 .. t0+72
#define WE (3 * CCH * CCH)

__device__ __forceinline__ u16 f2b(float f) {
  u32 u = __builtin_bit_cast(u32, f);
  u = (u + 0x7fffu + ((u >> 16) & 1u)) >> 16;   // RNE
  return (u16)u;
}
__device__ __forceinline__ float b2f(u16 h) {
  return __builtin_bit_cast(float, ((u32)h) << 16);
}

// ---- x (B,C,T) f32 -> xt (B,T,C) bf16 ----
__global__ __launch_bounds__(256) void k_tin(const float* __restrict__ x, u16* __restrict__ xt,
                                             int B, int T) {
  __shared__ float tile[32][36];
  int nt = T >> 5;
  int bid = blockIdx.x;
  int b = bid / (6 * nt);
  int rem = bid % (6 * nt);
  int cb = rem / nt, tb = rem % nt;
  int tid = threadIdx.x;
  {
    int c = tid >> 3, seg = tid & 7;
    const float* src = x + ((size_t)b * CCH + cb * 32 + c) * T + tb * 32 + seg * 4;
    float4 v = *(const float4*)src;
    tile[c][seg * 4 + 0] = v.x; tile[c][seg * 4 + 1] = v.y;
    tile[c][seg * 4 + 2] = v.z; tile[c][seg * 4 + 3] = v.w;
  }
  __syncthreads();
  {
    int t = tid >> 3, cs = tid & 7;
    u16* dst = xt + ((size_t)b * T + tb * 32 + t) * CCH + cb * 32 + cs * 4;
    ushort4 o;
    o.x = f2b(tile[cs * 4 + 0][t]); o.y = f2b(tile[cs * 4 + 1][t]);
    o.z = f2b(tile[cs * 4 + 2][t]); o.w = f2b(tile[cs * 4 + 3][t]);
    *(ushort4*)dst = o;
  }
}

// ---- weights (O,I,3) f32 -> (3,O,I) bf16 ----
__global__ __launch_bounds__(256) void k_wconv(const float* __restrict__ w, u16* __restrict__ dst) {
  int i = blockIdx.x * 256 + threadIdx.x;
  if (i >= 3 * CCH * CCH) return;
  int k = i / (CCH * CCH);
  int rem = i - k * (CCH * CCH);
  int o = rem / CCH, ii = rem - o * CCH;
  dst[i] = f2b(w[(o * CCH + ii) * 3 + k]);
}

// ---- emb (K,C) f32 -> bf16 + ||e||^2 f32 ----
__global__ __launch_bounds__(64) void k_emb(const float* __restrict__ emb, u16* __restrict__ embb,
                                            float* __restrict__ e2) {
  int code = blockIdx.x, lane = threadIdx.x;
  float s = 0.f;
  for (int j = lane * 3; j < lane * 3 + 3; ++j) {
    float v = emb[code * CCH + j];
    embb[code * CCH + j] = f2b(v);
    s += v * v;
  }
  #pragma unroll
  for (int m = 1; m < 64; m <<= 1) s += __shfl_xor(s, m, 64);
  if (lane == 0) e2[code] = s;
}

__global__ void k_zero(int* hist, double* dsum) {
  int t = threadIdx.x;
  if (t < NCODES) hist[t] = 0;
  if (t == 0) *dsum = 0.0;
}

// ---- one conv stage, LDS -> LDS: out rows [ORIG, ORIG+16F) from in rows [ORIG-1, ORIG+16F] ----
template<int F, int ORIG, bool RELU>
__device__ __forceinline__ void conv_stage(const u16* __restrict__ inb, u16* __restrict__ outb,
                                           const u16* __restrict__ wk, const float* __restrict__ bias,
                                           int wv, int lr, int lg, int t0, int T) {
  const int oB = wv * 48;
  f32x4 acc[F][3];
  #pragma unroll
  for (int m = 0; m < F; ++m)
    #pragma unroll
    for (int n = 0; n < 3; ++n) acc[m][n] = f32x4{0.f, 0.f, 0.f, 0.f};
  const u16* abase = inb + lr * APITCH + lg * 8;
  const u16* wbase = wk + (size_t)(oB + lr) * CCH + lg * 8;
  #pragma unroll
  for (int cb = 0; cb < 6; ++cb) {
    const int ci = cb * 32;
    #pragma unroll
    for (int k = 0; k < 3; ++k) {
      s16x8 a[F];
      #pragma unroll
      for (int m = 0; m < F; ++m)
        a[m] = *(const s16x8*)(abase + (ORIG - 1 + 16 * m + k) * APITCH + ci);
      #pragma unroll
      for (int nf = 0; nf < 3; ++nf) {
        s16x8 bf = *(const s16x8*)(wbase + (size_t)(k * CCH + nf * 16) * CCH + ci);
        #pragma unroll
        for (int m = 0; m < F; ++m)
          acc[m][nf] = __builtin_amdgcn_mfma_f32_16x16x32_bf16(a[m], bf, acc[m][nf], 0, 0, 0);
      }
    }
  }
  float bv[3];
  #pragma unroll
  for (int nf = 0; nf < 3; ++nf) bv[nf] = bias[oB + nf * 16 + lr];
  #pragma unroll
  for (int m = 0; m < F; ++m) {
    #pragma unroll
    for (int nf = 0; nf < 3; ++nf) {
      int o = oB + nf * 16 + lr;
      #pragma unroll
      for (int r = 0; r < 4; ++r) {
        int row = ORIG + 16 * m + lg * 4 + r;
        int tok = t0 - HALO + row;
        float v = acc[m][nf][r] + bv[nf];
        if (RELU) v = fmaxf(v, 0.f);
        if (tok < 0 || tok >= T) v = 0.f;   // reference zero-pads EVERY conv at sequence edges
        outb[row * APITCH + o] = f2b(v);
      }
    }
  }
}

// ---- fully fused: stage x tile -> enc1 -> enc2 -> VQ -> dec1 -> dec2 -> dec3 -> f32 (B,C,T) out ----
__global__ __launch_bounds__(256, 2) void k_fused(
    const u16* __restrict__ xt, const u16* __restrict__ wts,
    const float* __restrict__ eb1, const float* __restrict__ eb2,
    const float* __restrict__ db1, const float* __restrict__ db2, const float* __restrict__ db3,
    const u16* __restrict__ embb, const float* __restrict__ e2,
    int* __restrict__ hist, double* __restrict__ dsum,
    float* __restrict__ xhat, int T) {
  __shared__ __align__(16) char smem[2 * ROWS * APITCH * 2];   // 65600 B: two ping-pong act buffers
  __shared__ int hs[NCODES];
  __shared__ float wsum[4];
  u16* buf0 = (u16*)smem;
  u16* buf1 = buf0 + ROWS * APITCH;
  const int tid = threadIdx.x;
  const int wv = tid >> 6, lane = tid & 63, lr = lane & 15, lg = lane >> 4;
  const int bid = blockIdx.x;
  const int b = bid >> 7, tile = bid & 127;   // T/64 = 128 tiles per batch
  const int t0 = tile * 64;
  if (tid < NCODES) hs[tid] = 0;

  // ---- stage x rows t0-9 .. t0+72 (82 rows x 192 ch), batched loads then batched LDS writes ----
  {
    const u16* src = xt + (size_t)b * T * CCH;
    uint4 v[8]; int ra[8], sa[8];
    #pragma unroll
    for (int i = 0; i < 8; ++i) {
      unsigned s = tid + i * 256u;
      int row = (int)(s / 24u), seg = (int)(s - (unsigned)row * 24u);
      ra[i] = row; sa[i] = seg;
      int tok = t0 - HALO + row;
      uint4 t = {0u, 0u, 0u, 0u};
      if (s < ROWS * 24u && tok >= 0 && tok < T)
        t = *(const uint4*)(src + (size_t)tok * CCH + seg * 8);
      v[i] = t;
    }
    #pragma unroll
    for (int i = 0; i < 8; ++i) {
      if (tid + i * 256u < ROWS * 24u)
        *(uint4*)(buf0 + ra[i] * APITCH + sa[i] * 8) = v[i];
    }
  }
  __syncthreads();

  conv_stage<5, 1, true >(buf0, buf1, wts + 0 * WE, eb1, wv, lr, lg, t0, T);  // h1
  __syncthreads();
  conv_stage<5, 1, false>(buf1, buf0, wts + 1 * WE, eb2, wv, lr, lg, t0, T);  // z_e
  __syncthreads();

  // ---- VQ on LDS z_e, own tokens = rows HALO..HALO+63; wave wv owns 16 tokens ----
  {
    const int row = HALO + wv * 16 + lr;
    const u16* zbase = buf0 + row * APITCH;
    f32x4 vacc[8];
    #pragma unroll
    for (int nf = 0; nf < 8; ++nf) vacc[nf] = f32x4{0.f, 0.f, 0.f, 0.f};
    #pragma unroll
    for (int cb = 0; cb < 6; ++cb) {
      const int ci = cb * 32;
      s16x8 a = *(const s16x8*)(zbase + ci + lg * 8);
      #pragma unroll
      for (int nf = 0; nf < 8; ++nf) {
        s16x8 bf = *(const s16x8*)(embb + (size_t)(nf * 16 + lr) * CCH + ci + lg * 8);
        vacc[nf] = __builtin_amdgcn_mfma_f32_16x16x32_bf16(a, bf, vacc[nf], 0, 0, 0);
      }
    }
    float z2 = 0.f;
    const u16* zr = zbase + lg * 48;
    #pragma unroll
    for (int j = 0; j < 48; j += 8) {
      s16x8 vv = *(const s16x8*)(zr + j);
      #pragma unroll
      for (int e = 0; e < 8; ++e) { float f = b2f((u16)vv[e]); z2 += f * f; }
    }
    z2 += __shfl_xor(z2, 16, 64);
    z2 += __shfl_xor(z2, 32, 64);
    float smin[4]; int imin[4];
    #pragma unroll
    for (int r = 0; r < 4; ++r) { smin[r] = 3.4e38f; imin[r] = 0; }
    #pragma unroll
    for (int nf = 0; nf < 8; ++nf) {
      int code = nf * 16 + lr;
      float ev = e2[code];
      #pragma unroll
      for (int r = 0; r < 4; ++r) {
        float sc = ev - 2.f * vacc[nf][r];
        if (sc < smin[r]) { smin[r] = sc; imin[r] = code; }
      }
    }
    #pragma unroll
    for (int m = 1; m < 16; m <<= 1) {
      #pragma unroll
      for (int r = 0; r < 4; ++r) {
        float so = __shfl_xor(smin[r], m, 64);
        int io = __shfl_xor(imin[r], m, 64);
        if (so < smin[r] || (so == smin[r] && io < imin[r])) { smin[r] = so; imin[r] = io; }
      }
    }
    float z2t[4];
    #pragma unroll
    for (int r = 0; r < 4; ++r) z2t[r] = __shfl(z2, lg * 4 + r, 64);
    float dpart = 0.f;
    if (lr == 0) {
      #pragma unroll
      for (int r = 0; r < 4; ++r) {
        dpart += z2t[r] + smin[r];
        atomicAdd(&hs[imin[r]], 1);
      }
    }
    #pragma unroll
    for (int m = 1; m < 64; m <<= 1) dpart += __shfl_xor(dpart, m, 64);
    if (lane == 0) wsum[wv] = dpart;
  }

  conv_stage<5, 1, true >(buf0, buf1, wts + 2 * WE, db1, wv, lr, lg, t0, T);  // h
  __syncthreads();

  // flush VQ stats (hs/wsum complete before the barrier above)
  if (tid == 0) {
    double tot = (double)wsum[0] + (double)wsum[1] + (double)wsum[2] + (double)wsum[3];
    atomicAdd(dsum, tot);
  }
  if (tid < NCODES && hs[tid] > 0) atomicAdd(&hist[tid], hs[tid]);

  conv_stage<5, 1, true >(buf1, buf0, wts + 3 * WE, db2, wv, lr, lg, t0, T);  // h2
  __syncthreads();

  // ---- stage 5: x_hat rows 9..72 (exactly own 64 tokens), keep acc in regs ----
  const int oB = wv * 48;
  f32x4 acc5[4][3];
  #pragma unroll
  for (int m = 0; m < 4; ++m)
    #pragma unroll
    for (int n = 0; n < 3; ++n) acc5[m][n] = f32x4{0.f, 0.f, 0.f, 0.f};
  {
    const u16* abase = buf0 + lr * APITCH + lg * 8;
    const u16* wbase = wts + 4 * WE + (size_t)(oB + lr) * CCH + lg * 8;
    #pragma unroll
    for (int cb = 0; cb < 6; ++cb) {
      const int ci = cb * 32;
      #pragma unroll
      for (int k = 0; k < 3; ++k) {
        s16x8 a[4];
        #pragma unroll
        for (int m = 0; m < 4; ++m)
          a[m] = *(const s16x8*)(abase + (8 + 16 * m + k) * APITCH + ci);
        #pragma unroll
        for (int nf = 0; nf < 3; ++nf) {
          s16x8 bf = *(const s16x8*)(wbase + (size_t)(k * CCH + nf * 16) * CCH + ci);
          #pragma unroll
          for (int m = 0; m < 4; ++m)
            acc5[m][nf] = __builtin_amdgcn_mfma_f32_16x16x32_bf16(a[m], bf, acc5[m][nf], 0, 0, 0);
        }
      }
    }
  }
  float bv[3];
  #pragma unroll
  for (int nf = 0; nf < 3; ++nf) bv[nf] = db3[oB + nf * 16 + lr];
  __syncthreads();                     // done reading buf0 -> reuse smem as f32 transpose tile
  float* ft = (float*)smem;            // [192][66]
  #pragma unroll
  for (int m = 0; m < 4; ++m) {
    #pragma unroll
    for (int nf = 0; nf < 3; ++nf) {
      int o = oB + nf * 16 + lr;
      #pragma unroll
      for (int r = 0; r < 4; ++r) {
        int tl = 16 * m + lg * 4 + r;
        ft[o * 66 + tl] = acc5[m][nf][r] + bv[nf];
      }
    }
  }
  __syncthreads();
  float* dstb = xhat + (size_t)b * CCH * T + t0;
  for (int s = tid; s < CCH * 64; s += 256) {
    int o = s >> 6, tl = s & 63;
    dstb[(size_t)o * T + tl] = ft[o * 66 + tl];
  }
}

__global__ __launch_bounds__(128) void k_fin(const int* __restrict__ hist,
                                             const double* __restrict__ dsum,
                                             float* __restrict__ out, int N, int ppos) {
  __shared__ float H[NCODES];
  int t = threadIdx.x;
  float p = (float)hist[t] / (float)N;
  H[t] = p * logf(p + 1e-10f);
  __syncthreads();
  if (t == 0) {
    float s = 0.f;
    for (int i = 0; i < NCODES; ++i) s += H[i];
    out[ppos] = expf(-s);
    out[0] = (float)(1.25 * (*dsum) / ((double)N * (double)CCH));
  }
}

extern "C" void kernel_launch(void* const* d_in, const int* in_sizes, int n_in,
                              void* d_out, int out_size, void* d_ws, size_t ws_size,
                              hipStream_t stream) {
  const int B = 16, T = 8192, N = B * T;
  const float* x   = (const float*)d_in[0];
  const float* ew1 = (const float*)d_in[1];
  const float* eb1 = (const float*)d_in[2];
  const float* ew2 = (const float*)d_in[3];
  const float* eb2 = (const float*)d_in[4];
  const float* emb = (const float*)d_in[5];
  const float* dw1 = (const float*)d_in[6];
  const float* db1 = (const float*)d_in[7];
  const float* dw2 = (const float*)d_in[8];
  const float* db2 = (const float*)d_in[9];
  const float* dw3 = (const float*)d_in[10];
  const float* db3 = (const float*)d_in[11];

  char* ws = (char*)d_ws;
  const size_t actSz = (size_t)B * T * CCH * 2;
  u16* bufA = (u16*)ws;                                // xt
  u16* wts  = (u16*)(ws + actSz);
  u16* embb = (u16*)(ws + actSz + (size_t)5 * WE * 2);
  float* e2 = (float*)((char*)embb + (size_t)NCODES * CCH * 2);
  int* hist = (int*)((char*)e2 + 512);
  double* dsum = (double*)((char*)hist + 512);

  const int wblocks = (3 * CCH * CCH + 255) / 256;
  k_wconv<<<wblocks, 256, 0, stream>>>(ew1, wts);
  k_wconv<<<wblocks, 256, 0, stream>>>(ew2, wts + WE);
  k_wconv<<<wblocks, 256, 0, stream>>>(dw1, wts + 2 * WE);
  k_wconv<<<wblocks, 256, 0, stream>>>(dw2, wts + 3 * WE);
  k_wconv<<<wblocks, 256, 0, stream>>>(dw3, wts + 4 * WE);
  k_emb<<<NCODES, 64, 0, stream>>>(emb, embb, e2);
  k_zero<<<1, 256, 0, stream>>>(hist, dsum);
  k_tin<<<B * 6 * (T / 32), 256, 0, stream>>>(x, bufA, B, T);

  k_fused<<<B * (T / 64), 256, 0, stream>>>(bufA, wts, eb1, eb2, db1, db2, db3,
                                            embb, e2, hist, dsum, (float*)d_out + 1, T);
  k_fin<<<1, 128, 0, stream>>>(hist, dsum, (float*)d_out, N, out_size - 1);
}

// Round 4
// 361.151 us; speedup vs baseline: 1.3881x; 1.1700x over previous
//
#include <hip/hip_runtime.h>
#include <hip/hip_bf16.h>
#include <stdint.h>

typedef short s16x8 __attribute__((ext_vector_type(8)));
typedef float f32x4 __attribute__((ext_vector_type(4)));
typedef unsigned int u32;
typedef unsigned short u16;

#define CCH 192
#define APITCH 200   // bf16 elems per LDS row; 400B pitch -> 2-way bank alias only (free)
#define NCODES 128
#define HALO 9
#define ROWS 82      // staged rows: tokens t0-9 .. t0+72
#define WE (3 * CCH * CCH)

__device__ __forceinline__ u16 f2b(float f) {
  u32 u = __builtin_bit_cast(u32, f);
  u = (u + 0x7fffu + ((u >> 16) & 1u)) >> 16;   // RNE
  return (u16)u;
}
__device__ __forceinline__ float b2f(u16 h) {
  return __builtin_bit_cast(float, ((u32)h) << 16);
}

// ---- x (B,C,T) f32 -> xt (B,T,C) bf16 ----
__global__ __launch_bounds__(256) void k_tin(const float* __restrict__ x, u16* __restrict__ xt,
                                             int B, int T) {
  __shared__ float tile[32][36];
  int nt = T >> 5;
  int bid = blockIdx.x;
  int b = bid / (6 * nt);
  int rem = bid % (6 * nt);
  int cb = rem / nt, tb = rem % nt;
  int tid = threadIdx.x;
  {
    int c = tid >> 3, seg = tid & 7;
    const float* src = x + ((size_t)b * CCH + cb * 32 + c) * T + tb * 32 + seg * 4;
    float4 v = *(const float4*)src;
    tile[c][seg * 4 + 0] = v.x; tile[c][seg * 4 + 1] = v.y;
    tile[c][seg * 4 + 2] = v.z; tile[c][seg * 4 + 3] = v.w;
  }
  __syncthreads();
  {
    int t = tid >> 3, cs = tid & 7;
    u16* dst = xt + ((size_t)b * T + tb * 32 + t) * CCH + cb * 32 + cs * 4;
    ushort4 o;
    o.x = f2b(tile[cs * 4 + 0][t]); o.y = f2b(tile[cs * 4 + 1][t]);
    o.z = f2b(tile[cs * 4 + 2][t]); o.w = f2b(tile[cs * 4 + 3][t]);
    *(ushort4*)dst = o;
  }
}

// ---- weights (O,I,3) f32 -> (3,O,I) bf16 ----
__global__ __launch_bounds__(256) void k_wconv(const float* __restrict__ w, u16* __restrict__ dst) {
  int i = blockIdx.x * 256 + threadIdx.x;
  if (i >= 3 * CCH * CCH) return;
  int k = i / (CCH * CCH);
  int rem = i - k * (CCH * CCH);
  int o = rem / CCH, ii = rem - o * CCH;
  dst[i] = f2b(w[(o * CCH + ii) * 3 + k]);
}

// ---- emb (K,C) f32 -> bf16 + ||e||^2 f32 ----
__global__ __launch_bounds__(64) void k_emb(const float* __restrict__ emb, u16* __restrict__ embb,
                                            float* __restrict__ e2) {
  int code = blockIdx.x, lane = threadIdx.x;
  float s = 0.f;
  for (int j = lane * 3; j < lane * 3 + 3; ++j) {
    float v = emb[code * CCH + j];
    embb[code * CCH + j] = f2b(v);
    s += v * v;
  }
  #pragma unroll
  for (int m = 1; m < 64; m <<= 1) s += __shfl_xor(s, m, 64);
  if (lane == 0) e2[code] = s;
}

__global__ void k_zero(int* hist, double* dsum) {
  int t = threadIdx.x;
  if (t < NCODES) hist[t] = 0;
  if (t == 0) *dsum = 0.0;
}

// ---- one conv stage, LDS -> LDS, software-pipelined ----
// out rows [ORIG, ORIG+16F) from in rows [ORIG-1, ORIG+16F]
template<int F, int ORIG, bool RELU>
__device__ __forceinline__ void conv_stage(const u16* __restrict__ inb, u16* __restrict__ outb,
                                           const u16* __restrict__ wk, const float* __restrict__ bias,
                                           int wv, int lr, int lg, int t0, int T) {
  const int oB = wv * 48;
  f32x4 acc[F][3];
  #pragma unroll
  for (int m = 0; m < F; ++m)
    #pragma unroll
    for (int n = 0; n < 3; ++n) acc[m][n] = f32x4{0.f, 0.f, 0.f, 0.f};
  const u16* abase = inb + lr * APITCH + lg * 8;
  const u16* wbase = wk + (size_t)(oB + lr) * CCH + lg * 8;
  s16x8 w[2][3][3];   // weight double-buffer (cb, cb+1)
  s16x8 a[2][F];      // activation ping-pong ((cb,k), next)
  #pragma unroll
  for (int kk = 0; kk < 3; ++kk)
    #pragma unroll
    for (int nf = 0; nf < 3; ++nf)
      w[0][kk][nf] = *(const s16x8*)(wbase + ((size_t)kk * CCH + nf * 16) * CCH);
  #pragma unroll
  for (int m = 0; m < F; ++m)
    a[0][m] = *(const s16x8*)(abase + (ORIG - 1 + 16 * m) * APITCH);
  #pragma unroll
  for (int it = 0; it < 18; ++it) {
    const int cb = it / 3, k = it % 3;
    const int cw = cb & 1, ca = it & 1;
    if (k == 0 && cb < 5) {               // prefetch next cb's 9 weight frags (L2)
      const int nci = (cb + 1) * 32;
      #pragma unroll
      for (int kk = 0; kk < 3; ++kk)
        #pragma unroll
        for (int nf = 0; nf < 3; ++nf)
          w[cw ^ 1][kk][nf] = *(const s16x8*)(wbase + ((size_t)kk * CCH + nf * 16) * CCH + nci);
    }
    if (it < 17) {                        // prefetch next step's F a-frags (LDS)
      const int nit = it + 1, ncb = nit / 3, nk = nit % 3, nci = ncb * 32;
      #pragma unroll
      for (int m = 0; m < F; ++m)
        a[ca ^ 1][m] = *(const s16x8*)(abase + (ORIG - 1 + 16 * m + nk) * APITCH + nci);
    }
    #pragma unroll
    for (int nf = 0; nf < 3; ++nf)
      #pragma unroll
      for (int m = 0; m < F; ++m)
        acc[m][nf] = __builtin_amdgcn_mfma_f32_16x16x32_bf16(a[ca][m], w[cw][k][nf], acc[m][nf], 0, 0, 0);
  }
  float bv[3];
  #pragma unroll
  for (int nf = 0; nf < 3; ++nf) bv[nf] = bias[oB + nf * 16 + lr];
  #pragma unroll
  for (int m = 0; m < F; ++m) {
    #pragma unroll
    for (int nf = 0; nf < 3; ++nf) {
      int o = oB + nf * 16 + lr;
      #pragma unroll
      for (int r = 0; r < 4; ++r) {
        int row = ORIG + 16 * m + lg * 4 + r;
        int tok = t0 - HALO + row;
        float v = acc[m][nf][r] + bv[nf];
        if (RELU) v = fmaxf(v, 0.f);
        if (tok < 0 || tok >= T) v = 0.f;   // reference zero-pads EVERY conv at sequence edges
        outb[row * APITCH + o] = f2b(v);
      }
    }
  }
}

// ---- fully fused: stage x tile -> enc1 -> enc2 -> VQ -> dec1 -> dec2 -> dec3 -> f32 (B,C,T) out ----
__global__ __launch_bounds__(256, 2) void k_fused(
    const u16* __restrict__ xt, const u16* __restrict__ wts,
    const float* __restrict__ eb1, const float* __restrict__ eb2,
    const float* __restrict__ db1, const float* __restrict__ db2, const float* __restrict__ db3,
    const u16* __restrict__ embb, const float* __restrict__ e2,
    int* __restrict__ hist, double* __restrict__ dsum,
    float* __restrict__ xhat, int T) {
  __shared__ __align__(16) char smem[2 * ROWS * APITCH * 2];   // 65600 B: two ping-pong act buffers
  __shared__ int hs[NCODES];
  __shared__ float wsum[4];
  u16* buf0 = (u16*)smem;
  u16* buf1 = buf0 + ROWS * APITCH;
  const int tid = threadIdx.x;
  const int wv = tid >> 6, lane = tid & 63, lr = lane & 15, lg = lane >> 4;
  const int bid = blockIdx.x;
  const int b = bid >> 7, tile = bid & 127;   // T/64 = 128 tiles per batch
  const int t0 = tile * 64;
  if (tid < NCODES) hs[tid] = 0;

  // ---- stage x rows t0-9 .. t0+72 (82 rows x 192 ch) ----
  {
    const u16* src = xt + (size_t)b * T * CCH;
    uint4 v[8]; int ra[8], sa[8];
    #pragma unroll
    for (int i = 0; i < 8; ++i) {
      unsigned s = tid + i * 256u;
      int row = (int)(s / 24u), seg = (int)(s - (unsigned)row * 24u);
      ra[i] = row; sa[i] = seg;
      int tok = t0 - HALO + row;
      uint4 t = {0u, 0u, 0u, 0u};
      if (s < ROWS * 24u && tok >= 0 && tok < T)
        t = *(const uint4*)(src + (size_t)tok * CCH + seg * 8);
      v[i] = t;
    }
    #pragma unroll
    for (int i = 0; i < 8; ++i) {
      if (tid + i * 256u < ROWS * 24u)
        *(uint4*)(buf0 + ra[i] * APITCH + sa[i] * 8) = v[i];
    }
  }
  __syncthreads();

  conv_stage<5, 1, true >(buf0, buf1, wts + 0 * WE, eb1, wv, lr, lg, t0, T);  // h1
  __syncthreads();
  conv_stage<5, 1, false>(buf1, buf0, wts + 1 * WE, eb2, wv, lr, lg, t0, T);  // z_e
  __syncthreads();

  // ---- VQ on LDS z_e, own tokens = rows HALO..HALO+63; wave wv owns 16 tokens ----
  {
    const int row = HALO + wv * 16 + lr;
    const u16* zbase = buf0 + row * APITCH;
    f32x4 vacc[8];
    #pragma unroll
    for (int nf = 0; nf < 8; ++nf) vacc[nf] = f32x4{0.f, 0.f, 0.f, 0.f};
    #pragma unroll
    for (int cb = 0; cb < 6; ++cb) {
      const int ci = cb * 32;
      s16x8 a = *(const s16x8*)(zbase + ci + lg * 8);
      #pragma unroll
      for (int nf = 0; nf < 8; ++nf) {
        s16x8 bf = *(const s16x8*)(embb + (size_t)(nf * 16 + lr) * CCH + ci + lg * 8);
        vacc[nf] = __builtin_amdgcn_mfma_f32_16x16x32_bf16(a, bf, vacc[nf], 0, 0, 0);
      }
    }
    float z2 = 0.f;
    const u16* zr = zbase + lg * 48;
    #pragma unroll
    for (int j = 0; j < 48; j += 8) {
      s16x8 vv = *(const s16x8*)(zr + j);
      #pragma unroll
      for (int e = 0; e < 8; ++e) { float f = b2f((u16)vv[e]); z2 += f * f; }
    }
    z2 += __shfl_xor(z2, 16, 64);
    z2 += __shfl_xor(z2, 32, 64);
    float smin[4]; int imin[4];
    #pragma unroll
    for (int r = 0; r < 4; ++r) { smin[r] = 3.4e38f; imin[r] = 0; }
    #pragma unroll
    for (int nf = 0; nf < 8; ++nf) {
      int code = nf * 16 + lr;
      float ev = e2[code];
      #pragma unroll
      for (int r = 0; r < 4; ++r) {
        float sc = ev - 2.f * vacc[nf][r];
        if (sc < smin[r]) { smin[r] = sc; imin[r] = code; }
      }
    }
    #pragma unroll
    for (int m = 1; m < 16; m <<= 1) {
      #pragma unroll
      for (int r = 0; r < 4; ++r) {
        float so = __shfl_xor(smin[r], m, 64);
        int io = __shfl_xor(imin[r], m, 64);
        if (so < smin[r] || (so == smin[r] && io < imin[r])) { smin[r] = so; imin[r] = io; }
      }
    }
    float z2t[4];
    #pragma unroll
    for (int r = 0; r < 4; ++r) z2t[r] = __shfl(z2, lg * 4 + r, 64);
    float dpart = 0.f;
    if (lr == 0) {
      #pragma unroll
      for (int r = 0; r < 4; ++r) {
        dpart += z2t[r] + smin[r];
        atomicAdd(&hs[imin[r]], 1);
      }
    }
    #pragma unroll
    for (int m = 1; m < 64; m <<= 1) dpart += __shfl_xor(dpart, m, 64);
    if (lane == 0) wsum[wv] = dpart;
  }

  conv_stage<5, 1, true >(buf0, buf1, wts + 2 * WE, db1, wv, lr, lg, t0, T);  // h
  __syncthreads();

  // flush VQ stats (hs/wsum complete before the barrier above)
  if (tid == 0) {
    double tot = (double)wsum[0] + (double)wsum[1] + (double)wsum[2] + (double)wsum[3];
    atomicAdd(dsum, tot);
  }
  if (tid < NCODES && hs[tid] > 0) atomicAdd(&hist[tid], hs[tid]);

  conv_stage<5, 1, true >(buf1, buf0, wts + 3 * WE, db2, wv, lr, lg, t0, T);  // h2
  __syncthreads();

  // ---- stage 5: x_hat rows 9..72 (exactly own 64 tokens), acc in regs, pipelined ----
  const int oB = wv * 48;
  f32x4 acc5[4][3];
  #pragma unroll
  for (int m = 0; m < 4; ++m)
    #pragma unroll
    for (int n = 0; n < 3; ++n) acc5[m][n] = f32x4{0.f, 0.f, 0.f, 0.f};
  {
    const u16* abase = buf0 + lr * APITCH + lg * 8;
    const u16* wbase = wts + 4 * WE + (size_t)(oB + lr) * CCH + lg * 8;
    s16x8 w[2][3][3];
    s16x8 a[2][4];
    #pragma unroll
    for (int kk = 0; kk < 3; ++kk)
      #pragma unroll
      for (int nf = 0; nf < 3; ++nf)
        w[0][kk][nf] = *(const s16x8*)(wbase + ((size_t)kk * CCH + nf * 16) * CCH);
    #pragma unroll
    for (int m = 0; m < 4; ++m)
      a[0][m] = *(const s16x8*)(abase + (8 + 16 * m) * APITCH);
    #pragma unroll
    for (int it = 0; it < 18; ++it) {
      const int cb = it / 3, k = it % 3;
      const int cw = cb & 1, ca = it & 1;
      if (k == 0 && cb < 5) {
        const int nci = (cb + 1) * 32;
        #pragma unroll
        for (int kk = 0; kk < 3; ++kk)
          #pragma unroll
          for (int nf = 0; nf < 3; ++nf)
            w[cw ^ 1][kk][nf] = *(const s16x8*)(wbase + ((size_t)kk * CCH + nf * 16) * CCH + nci);
      }
      if (it < 17) {
        const int nit = it + 1, ncb = nit / 3, nk = nit % 3, nci = ncb * 32;
        #pragma unroll
        for (int m = 0; m < 4; ++m)
          a[ca ^ 1][m] = *(const s16x8*)(abase + (8 + 16 * m + nk) * APITCH + nci);
      }
      #pragma unroll
      for (int nf = 0; nf < 3; ++nf)
        #pragma unroll
        for (int m = 0; m < 4; ++m)
          acc5[m][nf] = __builtin_amdgcn_mfma_f32_16x16x32_bf16(a[ca][m], w[cw][k][nf], acc5[m][nf], 0, 0, 0);
    }
  }
  float bv[3];
  #pragma unroll
  for (int nf = 0; nf < 3; ++nf) bv[nf] = db3[oB + nf * 16 + lr];
  __syncthreads();                     // done reading buf0 -> reuse smem as f32 transpose tile
  float* ft = (float*)smem;            // [192][66]
  #pragma unroll
  for (int m = 0; m < 4; ++m) {
    #pragma unroll
    for (int nf = 0; nf < 3; ++nf) {
      int o = oB + nf * 16 + lr;
      #pragma unroll
      for (int r = 0; r < 4; ++r) {
        int tl = 16 * m + lg * 4 + r;
        ft[o * 66 + tl] = acc5[m][nf][r] + bv[nf];
      }
    }
  }
  __syncthreads();
  float* dstb = xhat + (size_t)b * CCH * T + t0;
  for (int s = tid; s < CCH * 64; s += 256) {
    int o = s >> 6, tl = s & 63;
    dstb[(size_t)o * T + tl] = ft[o * 66 + tl];
  }
}

__global__ __launch_bounds__(128) void k_fin(const int* __restrict__ hist,
                                             const double* __restrict__ dsum,
                                             float* __restrict__ out, int N, int ppos) {
  __shared__ float H[NCODES];
  int t = threadIdx.x;
  float p = (float)hist[t] / (float)N;
  H[t] = p * logf(p + 1e-10f);
  __syncthreads();
  if (t == 0) {
    float s = 0.f;
    for (int i = 0; i < NCODES; ++i) s += H[i];
    out[ppos] = expf(-s);
    out[0] = (float)(1.25 * (*dsum) / ((double)N * (double)CCH));
  }
}

extern "C" void kernel_launch(void* const* d_in, const int* in_sizes, int n_in,
                              void* d_out, int out_size, void* d_ws, size_t ws_size,
                              hipStream_t stream) {
  const int B = 16, T = 8192, N = B * T;
  const float* x   = (const float*)d_in[0];
  const float* ew1 = (const float*)d_in[1];
  const float* eb1 = (const float*)d_in[2];
  const float* ew2 = (const float*)d_in[3];
  const float* eb2 = (const float*)d_in[4];
  const float* emb = (const float*)d_in[5];
  const float* dw1 = (const float*)d_in[6];
  const float* db1 = (const float*)d_in[7];
  const float* dw2 = (const float*)d_in[8];
  const float* db2 = (const float*)d_in[9];
  const float* dw3 = (const float*)d_in[10];
  const float* db3 = (const float*)d_in[11];

  char* ws = (char*)d_ws;
  const size_t actSz = (size_t)B * T * CCH * 2;
  u16* bufA = (u16*)ws;                                // xt
  u16* wts  = (u16*)(ws + actSz);
  u16* embb = (u16*)(ws + actSz + (size_t)5 * WE * 2);
  float* e2 = (float*)((char*)embb + (size_t)NCODES * CCH * 2);
  int* hist = (int*)((char*)e2 + 512);
  double* dsum = (double*)((char*)hist + 512);

  const int wblocks = (3 * CCH * CCH + 255) / 256;
  k_wconv<<<wblocks, 256, 0, stream>>>(ew1, wts);
  k_wconv<<<wblocks, 256, 0, stream>>>(ew2, wts + WE);
  k_wconv<<<wblocks, 256, 0, stream>>>(dw1, wts + 2 * WE);
  k_wconv<<<wblocks, 256, 0, stream>>>(dw2, wts + 3 * WE);
  k_wconv<<<wblocks, 256, 0, stream>>>(dw3, wts + 4 * WE);
  k_emb<<<NCODES, 64, 0, stream>>>(emb, embb, e2);
  k_zero<<<1, 256, 0, stream>>>(hist, dsum);
  k_tin<<<B * 6 * (T / 32), 256, 0, stream>>>(x, bufA, B, T);

  k_fused<<<B * (T / 64), 256, 0, stream>>>(bufA, wts, eb1, eb2, db1, db2, db3,
                                            embb, e2, hist, dsum, (float*)d_out + 1, T);
  k_fin<<<1, 128, 0, stream>>>(hist, dsum, (float*)d_out, N, out_size - 1);
}